// Round 1
// baseline (830.149 us; speedup 1.0000x reference)
//
#include <hip/hip_runtime.h>
#include <hip/hip_bf16.h>

// SparseMLP: per-expert  out = gelu_tanh(x @ w1^T) @ w2
// E=8, T=2048, H=1024, F=4096. fp32 in/out, bf16 MFMA compute.

typedef __bf16 bf16x8 __attribute__((ext_vector_type(8)));
typedef float  f32x4  __attribute__((ext_vector_type(4)));

__device__ inline unsigned short f2b(float f) {
    unsigned u = __float_as_uint(f);
    u += 0x7fff + ((u >> 16) & 1);   // round-to-nearest-even
    return (unsigned short)(u >> 16);
}

// ---------------- cast fp32 -> bf16 (flat, vectorized) ----------------
__global__ void cast_f32_bf16(const float* __restrict__ in,
                              unsigned short* __restrict__ out, int n4) {
    int i = blockIdx.x * 256 + threadIdx.x;
    if (i >= n4) return;
    float4 v = ((const float4*)in)[i];
    ushort4 o;
    o.x = f2b(v.x); o.y = f2b(v.y); o.z = f2b(v.z); o.w = f2b(v.w);
    ((ushort4*)out)[i] = o;
}

// ------------- transpose-cast w2: fp32 [E,F,H] -> bf16 [E,H,F] -------------
__global__ void transpose_cast(const float* __restrict__ in,
                               unsigned short* __restrict__ out, int F, int H) {
    __shared__ float tile[32][33];
    const int e = blockIdx.z;
    const int f0 = blockIdx.y * 32, h0 = blockIdx.x * 32;
    const float* src = in + (long long)e * F * H;
    unsigned short* dst = out + (long long)e * F * H;
    const int tx = threadIdx.x, ty = threadIdx.y;   // 32 x 8
#pragma unroll
    for (int i = 0; i < 32; i += 8)
        tile[ty + i][tx] = src[(long long)(f0 + ty + i) * H + h0 + tx];
    __syncthreads();
#pragma unroll
    for (int i = 0; i < 32; i += 8)
        dst[(long long)(h0 + ty + i) * F + f0 + tx] = f2b(tile[tx][ty + i]);
}

// ---------------- m97-style bf16 GEMM, C = A @ B^T ----------------
// A: [E][M][K] bf16 (K-major), B: [E][N][K] bf16 (K-major), C: [E][M][N]
// 128x128 tile, BK=64, 256 threads (4 waves), wave computes 64x64 (4x4 MFMA tiles)
template <bool GELU, typename CT>
__global__ __launch_bounds__(256) void gemm_bt(
    const unsigned short* __restrict__ A,
    const unsigned short* __restrict__ B,
    CT* __restrict__ C, int M, int N, int K) {
    const int e = blockIdx.z;
    A += (long long)e * M * K;
    B += (long long)e * N * K;
    C += (long long)e * M * N;
    const int bm = blockIdx.y * 128, bn = blockIdx.x * 128;

    __shared__ unsigned short sA[128 * 64];
    __shared__ unsigned short sB[128 * 64];

    const int tid  = threadIdx.x;
    const int lane = tid & 63;
    const int wave = tid >> 6;
    const int quad = lane >> 4, ln = lane & 15;
    const int wm = (wave & 1) * 64, wn = (wave >> 1) * 64;

    f32x4 acc[4][4] = {};

    for (int k0 = 0; k0 < K; k0 += 64) {
        // ---- stage A,B tiles (128x64 bf16 each) via async global->LDS, 16B/lane ----
#pragma unroll
        for (int r = 0; r < 4; ++r) {
            const int eoff = r * 2048 + tid * 8;       // element offset in tile
            const int row = eoff >> 6, col = eoff & 63;
            const unsigned short* ga = A + (long long)(bm + row) * K + k0 + col;
            const unsigned short* gb = B + (long long)(bn + row) * K + k0 + col;
            __builtin_amdgcn_global_load_lds(
                (const __attribute__((address_space(1))) void*)ga,
                (__attribute__((address_space(3))) void*)(&sA[eoff]), 16, 0, 0);
            __builtin_amdgcn_global_load_lds(
                (const __attribute__((address_space(1))) void*)gb,
                (__attribute__((address_space(3))) void*)(&sB[eoff]), 16, 0, 0);
        }
        __syncthreads();

        // ---- 2 x (K=32) MFMA steps ----
#pragma unroll
        for (int kk = 0; kk < 64; kk += 32) {
            bf16x8 af[4], bfr[4];
#pragma unroll
            for (int i = 0; i < 4; ++i) {
                af[i]  = *(const bf16x8*)&sA[(wm + i * 16 + ln) * 64 + kk + quad * 8];
                bfr[i] = *(const bf16x8*)&sB[(wn + i * 16 + ln) * 64 + kk + quad * 8];
            }
#pragma unroll
            for (int i = 0; i < 4; ++i)
#pragma unroll
                for (int j = 0; j < 4; ++j)
                    acc[i][j] = __builtin_amdgcn_mfma_f32_16x16x32_bf16(
                        af[i], bfr[j], acc[i][j], 0, 0, 0);
        }
        __syncthreads();
    }

    // ---- epilogue: C/D layout col=lane&15, row=quad*4+reg ----
#pragma unroll
    for (int i = 0; i < 4; ++i) {
        const int row = bm + wm + i * 16 + quad * 4;
#pragma unroll
        for (int j = 0; j < 4; ++j) {
            const int col = bn + wn + j * 16 + ln;
#pragma unroll
            for (int r = 0; r < 4; ++r) {
                float v = acc[i][j][r];
                if (GELU) {
                    // gelu_tanh(v) = v * sigmoid(2*0.79788456*(v + 0.044715 v^3))
                    float t = 1.5957691216057308f * (v + 0.044715f * v * v * v);
                    v = v / (1.0f + __expf(-t));
                }
                if constexpr (sizeof(CT) == 2) {
                    ((unsigned short*)C)[(long long)(row + r) * N + col] = f2b(v);
                } else {
                    ((float*)C)[(long long)(row + r) * N + col] = v;
                }
            }
        }
    }
}

extern "C" void kernel_launch(void* const* d_in, const int* in_sizes, int n_in,
                              void* d_out, int out_size, void* d_ws, size_t ws_size,
                              hipStream_t stream) {
    constexpr int E = 8, T = 2048, H = 1024, F = 4096;
    const float* x  = (const float*)d_in[0];   // [E,T,H]
    const float* w1 = (const float*)d_in[1];   // [E,F,H]
    const float* w2 = (const float*)d_in[2];   // [E,F,H]
    float* out = (float*)d_out;                // [E,T,H]

    unsigned short* xb  = (unsigned short*)d_ws;          // E*T*H bf16
    unsigned short* w1b = xb  + (size_t)E * T * H;        // E*F*H bf16
    unsigned short* w2t = w1b + (size_t)E * F * H;        // E*H*F bf16 (transposed)
    unsigned short* ab  = w2t + (size_t)E * F * H;        // E*T*F bf16 (gelu act)

    const int nx = E * T * H / 4, nw = E * F * H / 4;
    cast_f32_bf16<<<(nx + 255) / 256, 256, 0, stream>>>(x, xb, nx);
    cast_f32_bf16<<<(nw + 255) / 256, 256, 0, stream>>>(w1, w1b, nw);
    transpose_cast<<<dim3(H / 32, F / 32, E), dim3(32, 8), 0, stream>>>(w2, w2t, F, H);

    // GEMM1: a = gelu(x @ w1^T)   [M=T, N=F, K=H] -> bf16
    gemm_bt<true, unsigned short>
        <<<dim3(F / 128, T / 128, E), 256, 0, stream>>>(xb, w1b, ab, T, F, H);
    // GEMM2: out = a @ w2t^T      [M=T, N=H, K=F] -> fp32
    gemm_bt<false, float>
        <<<dim3(H / 128, T / 128, E), 256, 0, stream>>>(ab, w2t, out, T, H, F);
}

// Round 2
// 741.822 us; speedup vs baseline: 1.1191x; 1.1191x over previous
//
#include <hip/hip_runtime.h>
#include <hip/hip_bf16.h>

// SparseMLP: per-expert  out = gelu_tanh(x @ w1^T) @ w2
// E=8, T=2048, H=1024, F=4096. fp32 in/out, bf16 MFMA compute.
//
// R2: XOR-swizzled LDS layout (chunk ^= row&7) to kill the 16-bank aliasing
// seen in R1 (SQ_LDS_BANK_CONFLICT=5e7, ~12 extra cyc/ds_read_b128).

typedef __bf16 bf16x8 __attribute__((ext_vector_type(8)));
typedef float  f32x4  __attribute__((ext_vector_type(4)));

__device__ inline unsigned short f2b(float f) {
    unsigned u = __float_as_uint(f);
    u += 0x7fff + ((u >> 16) & 1);   // round-to-nearest-even
    return (unsigned short)(u >> 16);
}

// ---------------- cast fp32 -> bf16 (flat, vectorized) ----------------
__global__ void cast_f32_bf16(const float* __restrict__ in,
                              unsigned short* __restrict__ out, int n4) {
    int i = blockIdx.x * 256 + threadIdx.x;
    if (i >= n4) return;
    float4 v = ((const float4*)in)[i];
    ushort4 o;
    o.x = f2b(v.x); o.y = f2b(v.y); o.z = f2b(v.z); o.w = f2b(v.w);
    ((ushort4*)out)[i] = o;
}

// ------------- transpose-cast w2: fp32 [E,F,H] -> bf16 [E,H,F] -------------
__global__ void transpose_cast(const float* __restrict__ in,
                               unsigned short* __restrict__ out, int F, int H) {
    __shared__ float tile[32][33];
    const int e = blockIdx.z;
    const int f0 = blockIdx.y * 32, h0 = blockIdx.x * 32;
    const float* src = in + (long long)e * F * H;
    unsigned short* dst = out + (long long)e * F * H;
    const int tx = threadIdx.x, ty = threadIdx.y;   // 32 x 8
#pragma unroll
    for (int i = 0; i < 32; i += 8)
        tile[ty + i][tx] = src[(long long)(f0 + ty + i) * H + h0 + tx];
    __syncthreads();
#pragma unroll
    for (int i = 0; i < 32; i += 8)
        dst[(long long)(h0 + ty + i) * F + f0 + tx] = f2b(tile[tx][ty + i]);
}

// ---------------- m97-style bf16 GEMM, C = A @ B^T, swizzled LDS ----------------
// A: [E][M][K] bf16 (K-major), B: [E][N][K] bf16 (K-major), C: [E][M][N]
// 128x128 tile, BK=64, 256 threads (4 waves), wave computes 64x64 (4x4 MFMA tiles)
// LDS tile: [128 rows][8 chunks of 8 bf16]; physical chunk = logical ^ (row&7).
template <bool GELU, typename CT>
__global__ __launch_bounds__(256) void gemm_bt(
    const unsigned short* __restrict__ A,
    const unsigned short* __restrict__ B,
    CT* __restrict__ C, int M, int N, int K) {
    const int e = blockIdx.z;
    A += (long long)e * M * K;
    B += (long long)e * N * K;
    C += (long long)e * M * N;
    const int bm = blockIdx.y * 128, bn = blockIdx.x * 128;

    __shared__ unsigned short sA[128 * 64];
    __shared__ unsigned short sB[128 * 64];

    const int tid  = threadIdx.x;
    const int lane = tid & 63;
    const int wave = tid >> 6;
    const int quad = lane >> 4, ln = lane & 15;
    const int wm = (wave & 1) * 64, wn = (wave >> 1) * 64;

    f32x4 acc[4][4] = {};

    for (int k0 = 0; k0 < K; k0 += 64) {
        // ---- stage A,B tiles (128x64 bf16 each) via async global->LDS, 16B/lane.
        // LDS dest is lane-contiguous (required); swizzle applied on global src:
        // LDS slot (row, chunk) receives global chunk (chunk ^ (row&7)).
#pragma unroll
        for (int r = 0; r < 4; ++r) {
            const int eoff = r * 2048 + tid * 8;       // dest element offset in tile
            const int row = eoff >> 6;
            const int cD  = (eoff >> 3) & 7;           // dest chunk
            const int scol = ((cD ^ (row & 7)) << 3);  // swizzled source column
            const unsigned short* ga = A + (long long)(bm + row) * K + k0 + scol;
            const unsigned short* gb = B + (long long)(bn + row) * K + k0 + scol;
            __builtin_amdgcn_global_load_lds(
                (const __attribute__((address_space(1))) void*)ga,
                (__attribute__((address_space(3))) void*)(&sA[eoff]), 16, 0, 0);
            __builtin_amdgcn_global_load_lds(
                (const __attribute__((address_space(1))) void*)gb,
                (__attribute__((address_space(3))) void*)(&sB[eoff]), 16, 0, 0);
        }
        __syncthreads();

        // ---- 2 x (K=32) MFMA steps ----
#pragma unroll
        for (int kk = 0; kk < 64; kk += 32) {
            bf16x8 af[4], bfr[4];
#pragma unroll
            for (int i = 0; i < 4; ++i) {
                const int ra = wm + i * 16 + ln;
                const int rb = wn + i * 16 + ln;
                const int cL = (kk >> 3) + quad;       // logical chunk
                af[i]  = *(const bf16x8*)&sA[ra * 64 + ((cL ^ (ra & 7)) << 3)];
                bfr[i] = *(const bf16x8*)&sB[rb * 64 + ((cL ^ (rb & 7)) << 3)];
            }
#pragma unroll
            for (int i = 0; i < 4; ++i)
#pragma unroll
                for (int j = 0; j < 4; ++j)
                    acc[i][j] = __builtin_amdgcn_mfma_f32_16x16x32_bf16(
                        af[i], bfr[j], acc[i][j], 0, 0, 0);
        }
        __syncthreads();
    }

    // ---- epilogue: C/D layout col=lane&15, row=quad*4+reg ----
#pragma unroll
    for (int i = 0; i < 4; ++i) {
        const int row = bm + wm + i * 16 + quad * 4;
#pragma unroll
        for (int j = 0; j < 4; ++j) {
            const int col = bn + wn + j * 16 + ln;
#pragma unroll
            for (int r = 0; r < 4; ++r) {
                float v = acc[i][j][r];
                if (GELU) {
                    // gelu_tanh(v) = v * sigmoid(2*0.79788456*(v + 0.044715 v^3))
                    float t = 1.5957691216057308f * (v + 0.044715f * v * v * v);
                    v = v / (1.0f + __expf(-t));
                }
                if constexpr (sizeof(CT) == 2) {
                    ((unsigned short*)C)[(long long)(row + r) * N + col] = f2b(v);
                } else {
                    ((float*)C)[(long long)(row + r) * N + col] = v;
                }
            }
        }
    }
}

extern "C" void kernel_launch(void* const* d_in, const int* in_sizes, int n_in,
                              void* d_out, int out_size, void* d_ws, size_t ws_size,
                              hipStream_t stream) {
    constexpr int E = 8, T = 2048, H = 1024, F = 4096;
    const float* x  = (const float*)d_in[0];   // [E,T,H]
    const float* w1 = (const float*)d_in[1];   // [E,F,H]
    const float* w2 = (const float*)d_in[2];   // [E,F,H]
    float* out = (float*)d_out;                // [E,T,H]

    unsigned short* xb  = (unsigned short*)d_ws;          // E*T*H bf16
    unsigned short* w1b = xb  + (size_t)E * T * H;        // E*F*H bf16
    unsigned short* w2t = w1b + (size_t)E * F * H;        // E*H*F bf16 (transposed)
    unsigned short* ab  = w2t + (size_t)E * F * H;        // E*T*F bf16 (gelu act)

    const int nx = E * T * H / 4, nw = E * F * H / 4;
    cast_f32_bf16<<<(nx + 255) / 256, 256, 0, stream>>>(x, xb, nx);
    cast_f32_bf16<<<(nw + 255) / 256, 256, 0, stream>>>(w1, w1b, nw);
    transpose_cast<<<dim3(H / 32, F / 32, E), dim3(32, 8), 0, stream>>>(w2, w2t, F, H);

    // GEMM1: a = gelu(x @ w1^T)   [M=T, N=F, K=H] -> bf16
    gemm_bt<true, unsigned short>
        <<<dim3(F / 128, T / 128, E), 256, 0, stream>>>(xb, w1b, ab, T, F, H);
    // GEMM2: out = a @ w2t^T      [M=T, N=H, K=F] -> fp32
    gemm_bt<false, float>
        <<<dim3(H / 128, T / 128, E), 256, 0, stream>>>(ab, w2t, out, T, H, F);
}

// Round 3
// 691.749 us; speedup vs baseline: 1.2001x; 1.0724x over previous
//
#include <hip/hip_runtime.h>
#include <hip/hip_bf16.h>

// SparseMLP: per-expert  out = gelu_tanh(x @ w1^T) @ w2
// E=8, T=2048, H=1024, F=4096. fp32 in/out, bf16 MFMA compute.
//
// R2: XOR-swizzled LDS (conflicts 5e7 -> 0).
// R3: 32x32x16 MFMA (2495 TF ceiling vs 2075, half the MFMA instr count) +
//     XCD-aware 1D raster for GEMM2 (R2 showed FETCH=557MB vs 201MB unique:
//     A-slabs duplicated across all 8 per-XCD L2s because XCD==x-tile; remap
//     so XCD==y-group -> 2MB of A pinned per XCD, B streams from L3).

typedef __bf16 bf16x8 __attribute__((ext_vector_type(8)));
typedef float  f32x16 __attribute__((ext_vector_type(16)));

__device__ inline unsigned short f2b(float f) {
    unsigned u = __float_as_uint(f);
    u += 0x7fff + ((u >> 16) & 1);   // round-to-nearest-even
    return (unsigned short)(u >> 16);
}

// ---------------- cast fp32 -> bf16 (flat, vectorized) ----------------
__global__ void cast_f32_bf16(const float* __restrict__ in,
                              unsigned short* __restrict__ out, int n4) {
    int i = blockIdx.x * 256 + threadIdx.x;
    if (i >= n4) return;
    float4 v = ((const float4*)in)[i];
    ushort4 o;
    o.x = f2b(v.x); o.y = f2b(v.y); o.z = f2b(v.z); o.w = f2b(v.w);
    ((ushort4*)out)[i] = o;
}

// ------------- transpose-cast w2: fp32 [E,F,H] -> bf16 [E,H,F] -------------
__global__ void transpose_cast(const float* __restrict__ in,
                               unsigned short* __restrict__ out, int F, int H) {
    __shared__ float tile[32][33];
    const int e = blockIdx.z;
    const int f0 = blockIdx.y * 32, h0 = blockIdx.x * 32;
    const float* src = in + (long long)e * F * H;
    unsigned short* dst = out + (long long)e * F * H;
    const int tx = threadIdx.x, ty = threadIdx.y;   // 32 x 8
#pragma unroll
    for (int i = 0; i < 32; i += 8)
        tile[ty + i][tx] = src[(long long)(f0 + ty + i) * H + h0 + tx];
    __syncthreads();
#pragma unroll
    for (int i = 0; i < 32; i += 8)
        dst[(long long)(h0 + ty + i) * F + f0 + tx] = f2b(tile[tx][ty + i]);
}

// ---------------- bf16 GEMM, C = A @ B^T, swizzled LDS, 32x32x16 MFMA ----------
// A: [E][M][K] bf16 (K-major), B: [E][N][K] bf16 (K-major), C: [E][M][N]
// 128x128 tile, BK=64, 256 threads (4 waves), wave computes 64x64 (2x2 of 32x32).
// LDS tile: [128 rows][8 chunks of 8 bf16]; physical chunk = logical ^ (row&7).
// RASTER1D (GEMM2): 1D grid, XCD = id&7 owns y-tiles {2*xcd, 2*xcd+1} so its
// two 1MB A-slabs pin in the 4MB per-XCD L2.
template <bool GELU, bool RASTER1D, typename CT>
__global__ __launch_bounds__(256) void gemm_bt(
    const unsigned short* __restrict__ A,
    const unsigned short* __restrict__ B,
    CT* __restrict__ C, int M, int N, int K) {
    int e, bm, bn;
    if constexpr (RASTER1D) {
        // grid = E*16*8 blocks; decode: XCD (id&7) -> y-pair, t&7 -> x-tile
        const int id = blockIdx.x;
        const int xcd = id & 7, s = id >> 3, t = s & 15;
        e  = s >> 4;
        bm = (xcd * 2 + (t >> 3)) * 128;
        bn = (t & 7) * 128;
    } else {
        e = blockIdx.z; bm = blockIdx.y * 128; bn = blockIdx.x * 128;
    }
    A += (long long)e * M * K;
    B += (long long)e * N * K;
    C += (long long)e * M * N;

    __shared__ unsigned short sA[128 * 64];
    __shared__ unsigned short sB[128 * 64];

    const int tid  = threadIdx.x;
    const int lane = tid & 63;
    const int wave = tid >> 6;
    const int half = lane >> 5, r32 = lane & 31;
    const int wm = (wave & 1) * 64, wn = (wave >> 1) * 64;

    f32x16 acc[2][2] = {};

    for (int k0 = 0; k0 < K; k0 += 64) {
        // ---- stage A,B tiles (128x64 bf16) via async global->LDS, 16B/lane.
        // LDS dest lane-contiguous (required); swizzle applied on global src.
#pragma unroll
        for (int r = 0; r < 4; ++r) {
            const int eoff = r * 2048 + tid * 8;       // dest element offset
            const int row = eoff >> 6;
            const int cD  = (eoff >> 3) & 7;           // dest chunk
            const int scol = ((cD ^ (row & 7)) << 3);  // swizzled source column
            const unsigned short* ga = A + (long long)(bm + row) * K + k0 + scol;
            const unsigned short* gb = B + (long long)(bn + row) * K + k0 + scol;
            __builtin_amdgcn_global_load_lds(
                (const __attribute__((address_space(1))) void*)ga,
                (__attribute__((address_space(3))) void*)(&sA[eoff]), 16, 0, 0);
            __builtin_amdgcn_global_load_lds(
                (const __attribute__((address_space(1))) void*)gb,
                (__attribute__((address_space(3))) void*)(&sB[eoff]), 16, 0, 0);
        }
        __syncthreads();

        // ---- 4 x (K=16) MFMA steps, 32x32x16 ----
#pragma unroll
        for (int ks = 0; ks < 4; ++ks) {
            bf16x8 af[2], bfr[2];
            const int cL = ks * 2 + half;              // logical chunk
#pragma unroll
            for (int i = 0; i < 2; ++i) {
                const int ra = wm + i * 32 + r32;
                const int rb = wn + i * 32 + r32;
                af[i]  = *(const bf16x8*)&sA[ra * 64 + ((cL ^ (ra & 7)) << 3)];
                bfr[i] = *(const bf16x8*)&sB[rb * 64 + ((cL ^ (rb & 7)) << 3)];
            }
#pragma unroll
            for (int i = 0; i < 2; ++i)
#pragma unroll
                for (int j = 0; j < 2; ++j)
                    acc[i][j] = __builtin_amdgcn_mfma_f32_32x32x16_bf16(
                        af[i], bfr[j], acc[i][j], 0, 0, 0);
        }
        __syncthreads();
    }

    // ---- epilogue: 32x32 C/D layout col=lane&31, row=(r&3)+8*(r>>2)+4*half ----
#pragma unroll
    for (int i = 0; i < 2; ++i) {
        const int row_base = bm + wm + i * 32;
#pragma unroll
        for (int j = 0; j < 2; ++j) {
            const int col = bn + wn + j * 32 + r32;
#pragma unroll
            for (int r = 0; r < 16; ++r) {
                const int row = row_base + (r & 3) + 8 * (r >> 2) + 4 * half;
                float v = acc[i][j][r];
                if (GELU) {
                    // gelu_tanh(v) = v * sigmoid(2*0.79788456*(v + 0.044715 v^3))
                    float t = 1.5957691216057308f * (v + 0.044715f * v * v * v);
                    v = v / (1.0f + __expf(-t));
                }
                if constexpr (sizeof(CT) == 2) {
                    ((unsigned short*)C)[(long long)row * N + col] = f2b(v);
                } else {
                    ((float*)C)[(long long)row * N + col] = v;
                }
            }
        }
    }
}

extern "C" void kernel_launch(void* const* d_in, const int* in_sizes, int n_in,
                              void* d_out, int out_size, void* d_ws, size_t ws_size,
                              hipStream_t stream) {
    constexpr int E = 8, T = 2048, H = 1024, F = 4096;
    const float* x  = (const float*)d_in[0];   // [E,T,H]
    const float* w1 = (const float*)d_in[1];   // [E,F,H]
    const float* w2 = (const float*)d_in[2];   // [E,F,H]
    float* out = (float*)d_out;                // [E,T,H]

    unsigned short* xb  = (unsigned short*)d_ws;          // E*T*H bf16
    unsigned short* w1b = xb  + (size_t)E * T * H;        // E*F*H bf16
    unsigned short* w2t = w1b + (size_t)E * F * H;        // E*H*F bf16 (transposed)
    unsigned short* ab  = w2t + (size_t)E * F * H;        // E*T*F bf16 (gelu act)

    const int nx = E * T * H / 4, nw = E * F * H / 4;
    cast_f32_bf16<<<(nx + 255) / 256, 256, 0, stream>>>(x, xb, nx);
    cast_f32_bf16<<<(nw + 255) / 256, 256, 0, stream>>>(w1, w1b, nw);
    transpose_cast<<<dim3(H / 32, F / 32, E), dim3(32, 8), 0, stream>>>(w2, w2t, F, H);

    // GEMM1: a = gelu(x @ w1^T)   [M=T, N=F, K=H] -> bf16 (natural raster:
    // XCD==x%8 pins 4 B-slices + 4MB A per XCD -> already L2-friendly)
    gemm_bt<true, false, unsigned short>
        <<<dim3(F / 128, T / 128, E), 256, 0, stream>>>(xb, w1b, ab, T, F, H);
    // GEMM2: out = a @ w2t^T      [M=T, N=H, K=F] -> fp32 (1D XCD raster)
    gemm_bt<false, true, float>
        <<<dim3(E * (T / 128) * (H / 128)), 256, 0, stream>>>(ab, w2t, out, T, H, F);
}